// Round 1
// baseline (1476.123 us; speedup 1.0000x reference)
//
#include <hip/hip_runtime.h>
#include <hip/hip_bf16.h>
#include <stdint.h>

#define D 128
#define NNODES 100000
#define NEDGES 800000
#define LDSTR 136   // LDS row stride in bf16 elems (128 + 8 pad -> 2-way bank alias, free)

typedef __bf16 bf16_t;
typedef bf16_t bf16x8 __attribute__((ext_vector_type(8)));
typedef float  f32x4  __attribute__((ext_vector_type(4)));

// ---- weight transpose+convert: dst[n*K + k] = (bf16) src[k*N + n]  (dst = W^T, row-major [N][K])
__global__ void wprep_kernel(const float* __restrict__ src, bf16_t* __restrict__ dst,
                             int K, int N) {
  int idx = blockIdx.x * blockDim.x + threadIdx.x;
  if (idx >= K * N) return;
  int n = idx / K;
  int k = idx - n * K;
  dst[idx] = (bf16_t)src[(size_t)k * N + n];
}

// ============================ EDGE KERNEL ============================
// Per block: 128 edges. e_in = [node[snd] | node[rcv] | edge] (K=384 = 3 chunks of 128).
// GEMM1 (K=384) -> relu -> GEMM2 (K=128) -> +be2 -> residual edge write + atomic scatter to agg.
__global__ __launch_bounds__(256) void edge_kernel(
    const float* __restrict__ node_f, const float* __restrict__ edge_f,
    const int* __restrict__ senders, const int* __restrict__ receivers,
    const bf16_t* __restrict__ W1T,   // [128][384] bf16 (We1^T)
    const float* __restrict__ be1,
    const bf16_t* __restrict__ W2T,   // [128][128] bf16 (We2^T)
    const float* __restrict__ be2,
    float* __restrict__ agg,          // [NNODES][128] f32 (aliases d_out node region, pre-zeroed)
    float* __restrict__ out_edges)    // [NEDGES][128] f32
{
  __shared__ bf16_t As[128 * LDSTR];
  __shared__ int s_snd[128];
  __shared__ int s_rcv[128];

  const int tid  = threadIdx.x;
  const int base = blockIdx.x * 128;

  if (tid < 128) s_snd[tid] = senders[base + tid];
  else           s_rcv[tid - 128] = receivers[base + tid - 128];

  const int lane = tid & 63;
  const int wave = tid >> 6;
  const int q    = lane >> 4;
  const int ln   = lane & 15;
  const int m0   = (wave & 1) * 64;   // row quadrant
  const int n0   = (wave >> 1) * 64;  // col quadrant

  f32x4 acc[4][4];
  #pragma unroll
  for (int i = 0; i < 4; i++)
    #pragma unroll
    for (int j = 0; j < 4; j++) acc[i][j] = {0.f, 0.f, 0.f, 0.f};

  const int sr = tid >> 1;         // staging row (2 threads/row)
  const int sc = (tid & 1) * 64;   // staging col base

  __syncthreads();  // s_snd/s_rcv ready

  // ---- GEMM1 over 3 K-chunks of 128 ----
  for (int c = 0; c < 3; ++c) {
    const float* src;
    if (c == 0)      src = node_f + (size_t)s_snd[sr] * D;
    else if (c == 1) src = node_f + (size_t)s_rcv[sr] * D;
    else             src = edge_f + (size_t)(base + sr) * D;
    #pragma unroll
    for (int v = 0; v < 8; ++v) {
      float4 f0 = ((const float4*)src)[(sc >> 2) + 2 * v];
      float4 f1 = ((const float4*)src)[(sc >> 2) + 2 * v + 1];
      bf16x8 b = {(bf16_t)f0.x, (bf16_t)f0.y, (bf16_t)f0.z, (bf16_t)f0.w,
                  (bf16_t)f1.x, (bf16_t)f1.y, (bf16_t)f1.z, (bf16_t)f1.w};
      *(bf16x8*)&As[sr * LDSTR + sc + v * 8] = b;
    }
    __syncthreads();
    #pragma unroll
    for (int kk = 0; kk < 128; kk += 32) {
      bf16x8 a[4], bb[4];
      #pragma unroll
      for (int i = 0; i < 4; i++)
        a[i] = *(const bf16x8*)&As[(m0 + i * 16 + ln) * LDSTR + kk + q * 8];
      const int kg = c * 128 + kk + q * 8;
      #pragma unroll
      for (int j = 0; j < 4; j++)
        bb[j] = *(const bf16x8*)&W1T[(size_t)(n0 + j * 16 + ln) * 384 + kg];
      #pragma unroll
      for (int i = 0; i < 4; i++)
        #pragma unroll
        for (int j = 0; j < 4; j++)
          acc[i][j] = __builtin_amdgcn_mfma_f32_16x16x32_bf16(a[i], bb[j], acc[i][j], 0, 0, 0);
    }
    __syncthreads();
  }

  // ---- h = relu(acc + be1) -> LDS (bf16, reuse As) ----
  #pragma unroll
  for (int i = 0; i < 4; i++)
    #pragma unroll
    for (int j = 0; j < 4; j++)
      #pragma unroll
      for (int r = 0; r < 4; r++) {
        int row = m0 + i * 16 + q * 4 + r;
        int col = n0 + j * 16 + ln;
        float v = acc[i][j][r] + be1[col];
        As[row * LDSTR + col] = (bf16_t)fmaxf(v, 0.f);
      }
  __syncthreads();

  // ---- GEMM2: e_upd = h @ We2 (K=128) ----
  f32x4 acc2[4][4];
  #pragma unroll
  for (int i = 0; i < 4; i++)
    #pragma unroll
    for (int j = 0; j < 4; j++) acc2[i][j] = {0.f, 0.f, 0.f, 0.f};

  #pragma unroll
  for (int kk = 0; kk < 128; kk += 32) {
    bf16x8 a[4], bb[4];
    #pragma unroll
    for (int i = 0; i < 4; i++)
      a[i] = *(const bf16x8*)&As[(m0 + i * 16 + ln) * LDSTR + kk + q * 8];
    #pragma unroll
    for (int j = 0; j < 4; j++)
      bb[j] = *(const bf16x8*)&W2T[(size_t)(n0 + j * 16 + ln) * 128 + kk + q * 8];
    #pragma unroll
    for (int i = 0; i < 4; i++)
      #pragma unroll
      for (int j = 0; j < 4; j++)
        acc2[i][j] = __builtin_amdgcn_mfma_f32_16x16x32_bf16(a[i], bb[j], acc2[i][j], 0, 0, 0);
  }

  // ---- epilogue: residual edge write + atomic scatter-add to agg ----
  #pragma unroll
  for (int i = 0; i < 4; i++)
    #pragma unroll
    for (int j = 0; j < 4; j++)
      #pragma unroll
      for (int r = 0; r < 4; r++) {
        int row = m0 + i * 16 + q * 4 + r;
        int col = n0 + j * 16 + ln;
        float v = acc2[i][j][r] + be2[col];
        size_t e = (size_t)(base + row);
        out_edges[e * D + col] = edge_f[e * D + col] + v;
        unsafeAtomicAdd(&agg[(size_t)s_rcv[row] * D + col], v);
      }
}

// ============================ NODE KERNEL ============================
// Per block: 128 nodes. n_in = [node | agg] (K=256 = 2 chunks of 128).
__global__ __launch_bounds__(256) void node_kernel(
    const float* __restrict__ node_f,
    const bf16_t* __restrict__ W1T,   // [128][256] bf16 (Wn1^T)
    const float* __restrict__ b1,
    const bf16_t* __restrict__ W2T,   // [128][128] bf16 (Wn2^T)
    const float* __restrict__ b2,
    const float* __restrict__ agg,    // d_out node region (read)
    float* __restrict__ out_nodes)    // same region (write — per-block row ownership)
{
  __shared__ bf16_t As[128 * LDSTR];

  const int tid    = threadIdx.x;
  const int base   = blockIdx.x * 128;
  const int nvalid = min(128, NNODES - base);

  const int lane = tid & 63;
  const int wave = tid >> 6;
  const int q    = lane >> 4;
  const int ln   = lane & 15;
  const int m0   = (wave & 1) * 64;
  const int n0   = (wave >> 1) * 64;

  f32x4 acc[4][4];
  #pragma unroll
  for (int i = 0; i < 4; i++)
    #pragma unroll
    for (int j = 0; j < 4; j++) acc[i][j] = {0.f, 0.f, 0.f, 0.f};

  const int sr = tid >> 1;
  const int sc = (tid & 1) * 64;
  const size_t src_row = (size_t)(base + min(sr, nvalid - 1));

  for (int c = 0; c < 2; ++c) {
    const float* src = (c == 0 ? node_f : agg) + src_row * D;
    #pragma unroll
    for (int v = 0; v < 8; ++v) {
      float4 f0 = ((const float4*)src)[(sc >> 2) + 2 * v];
      float4 f1 = ((const float4*)src)[(sc >> 2) + 2 * v + 1];
      bf16x8 b = {(bf16_t)f0.x, (bf16_t)f0.y, (bf16_t)f0.z, (bf16_t)f0.w,
                  (bf16_t)f1.x, (bf16_t)f1.y, (bf16_t)f1.z, (bf16_t)f1.w};
      *(bf16x8*)&As[sr * LDSTR + sc + v * 8] = b;
    }
    __syncthreads();
    #pragma unroll
    for (int kk = 0; kk < 128; kk += 32) {
      bf16x8 a[4], bb[4];
      #pragma unroll
      for (int i = 0; i < 4; i++)
        a[i] = *(const bf16x8*)&As[(m0 + i * 16 + ln) * LDSTR + kk + q * 8];
      const int kg = c * 128 + kk + q * 8;
      #pragma unroll
      for (int j = 0; j < 4; j++)
        bb[j] = *(const bf16x8*)&W1T[(size_t)(n0 + j * 16 + ln) * 256 + kg];
      #pragma unroll
      for (int i = 0; i < 4; i++)
        #pragma unroll
        for (int j = 0; j < 4; j++)
          acc[i][j] = __builtin_amdgcn_mfma_f32_16x16x32_bf16(a[i], bb[j], acc[i][j], 0, 0, 0);
    }
    __syncthreads();
  }

  #pragma unroll
  for (int i = 0; i < 4; i++)
    #pragma unroll
    for (int j = 0; j < 4; j++)
      #pragma unroll
      for (int r = 0; r < 4; r++) {
        int row = m0 + i * 16 + q * 4 + r;
        int col = n0 + j * 16 + ln;
        float v = acc[i][j][r] + b1[col];
        As[row * LDSTR + col] = (bf16_t)fmaxf(v, 0.f);
      }
  __syncthreads();

  f32x4 acc2[4][4];
  #pragma unroll
  for (int i = 0; i < 4; i++)
    #pragma unroll
    for (int j = 0; j < 4; j++) acc2[i][j] = {0.f, 0.f, 0.f, 0.f};

  #pragma unroll
  for (int kk = 0; kk < 128; kk += 32) {
    bf16x8 a[4], bb[4];
    #pragma unroll
    for (int i = 0; i < 4; i++)
      a[i] = *(const bf16x8*)&As[(m0 + i * 16 + ln) * LDSTR + kk + q * 8];
    #pragma unroll
    for (int j = 0; j < 4; j++)
      bb[j] = *(const bf16x8*)&W2T[(size_t)(n0 + j * 16 + ln) * 128 + kk + q * 8];
    #pragma unroll
    for (int i = 0; i < 4; i++)
      #pragma unroll
      for (int j = 0; j < 4; j++)
        acc2[i][j] = __builtin_amdgcn_mfma_f32_16x16x32_bf16(a[i], bb[j], acc2[i][j], 0, 0, 0);
  }

  #pragma unroll
  for (int i = 0; i < 4; i++)
    #pragma unroll
    for (int j = 0; j < 4; j++)
      #pragma unroll
      for (int r = 0; r < 4; r++) {
        int row = m0 + i * 16 + q * 4 + r;
        if (row < nvalid) {
          int col = n0 + j * 16 + ln;
          float v = acc2[i][j][r] + b2[col];
          size_t nidx = (size_t)(base + row);
          out_nodes[nidx * D + col] = node_f[nidx * D + col] + v;
        }
      }
}

extern "C" void kernel_launch(void* const* d_in, const int* in_sizes, int n_in,
                              void* d_out, int out_size, void* d_ws, size_t ws_size,
                              hipStream_t stream) {
  const float* node_f    = (const float*)d_in[0];
  const float* edge_f    = (const float*)d_in[1];
  const int*   senders   = (const int*)d_in[2];
  const int*   receivers = (const int*)d_in[3];
  const float* We1 = (const float*)d_in[4];
  const float* be1 = (const float*)d_in[5];
  const float* We2 = (const float*)d_in[6];
  const float* be2 = (const float*)d_in[7];
  const float* Wn1 = (const float*)d_in[8];
  const float* bn1 = (const float*)d_in[9];
  const float* Wn2 = (const float*)d_in[10];
  const float* bn2 = (const float*)d_in[11];

  float* out_nodes = (float*)d_out;                       // [NNODES][128] — doubles as agg
  float* out_edges = out_nodes + (size_t)NNODES * D;      // [NEDGES][128]

  bf16_t* W1T  = (bf16_t*)d_ws;        // 128*384
  bf16_t* W2T  = W1T  + 128 * 384;     // 128*128
  bf16_t* Wn1T = W2T  + 128 * 128;     // 128*256
  bf16_t* Wn2T = Wn1T + 128 * 256;     // 128*128

  // zero the agg region (harness poisons d_out with 0xAA before every launch)
  hipMemsetAsync(d_out, 0, (size_t)NNODES * D * sizeof(float), stream);

  wprep_kernel<<<(384 * 128 + 255) / 256, 256, 0, stream>>>(We1, W1T, 384, 128);
  wprep_kernel<<<(128 * 128 + 255) / 256, 256, 0, stream>>>(We2, W2T, 128, 128);
  wprep_kernel<<<(256 * 128 + 255) / 256, 256, 0, stream>>>(Wn1, Wn1T, 256, 128);
  wprep_kernel<<<(128 * 128 + 255) / 256, 256, 0, stream>>>(Wn2, Wn2T, 128, 128);

  edge_kernel<<<NEDGES / 128, 256, 0, stream>>>(
      node_f, edge_f, senders, receivers, W1T, be1, W2T, be2, out_nodes, out_edges);

  node_kernel<<<(NNODES + 127) / 128, 256, 0, stream>>>(
      node_f, Wn1T, bn1, Wn2T, bn2, out_nodes, out_nodes);
}